// Round 5
// baseline (4467.015 us; speedup 1.0000x reference)
//
#include <hip/hip_runtime.h>
#include <hip/hip_bf16.h>
#include <math.h>

#define N_ROWS 16384
#define HDIM   2048
#define M_CODES 64
#define NBLK   256      // N_ROWS / 64
#define CHUNK  32

// ---------------------------------------------------------------------------
// K1: per 64-row block: FLOAT32 distance matrix computed with BLAS-like
// rounding (sequential-k fmaf chain for x@w.T, numpy-pairwise f32 row norms),
// upcast to f64 -> single-thread literal transliteration of the reference's
// _lsa_square (buggy greedy JV). Also emits per-block column-sum partials.
// ---------------------------------------------------------------------------
__global__ __launch_bounds__(256) void dist_lsa_kernel(
    const float* __restrict__ x, const float* __restrict__ w,
    float* __restrict__ colsum_part,   // [NBLK][HDIM]
    int*   __restrict__ idx_ws,        // [N_ROWS]
    float* __restrict__ out_idx)       // d_out + 1 + N*H
{
    __shared__ float  xs [64][CHUNK + 4];
    __shared__ float  wsh[64][CHUNK + 4];
    __shared__ double C[64][65];
    __shared__ float  partial[128][17];   // 16 x 128-block partials per row
    __shared__ float  nxw[128];           // final norms: [0..63]=x, [64..127]=w

    const int t   = threadIdx.x;
    const int blk = blockIdx.x;
    const float* xb = x + (size_t)blk * 64 * HDIM;

    const int ty = t >> 4, tx = t & 15;
    const int r0 = ty * 4, c0 = tx * 4;
    float acc[4][4];
    #pragma unroll
    for (int i = 0; i < 4; ++i)
        #pragma unroll
        for (int j = 0; j < 4; ++j) acc[i][j] = 0.0f;

    // numpy pairwise 8-accumulator state (rows 0..127 own a row's norm)
    float r8[8];
    #pragma unroll
    for (int j = 0; j < 8; ++j) r8[j] = 0.0f;

    for (int hb = 0; hb < HDIM; hb += CHUNK) {
        __syncthreads();
        #pragma unroll
        for (int i = 0; i < 2; ++i) {
            int s = t * 2 + i;            // 0..511 float4 slots
            int r = s >> 3, c4 = s & 7;
            float4 vx = *reinterpret_cast<const float4*>(&xb[(size_t)r * HDIM + hb + c4 * 4]);
            *reinterpret_cast<float4*>(&xs[r][c4 * 4]) = vx;
            float4 vw = *reinterpret_cast<const float4*>(&w[(size_t)r * HDIM + hb + c4 * 4]);
            *reinterpret_cast<float4*>(&wsh[r][c4 * 4]) = vw;
        }
        __syncthreads();
        // ---- norms: numpy pairwise semantics, f32, NO fma contraction ----
        if (t < 128) {
            const float* row = (t < 64) ? &xs[t][0] : &wsh[t - 64][0];
            #pragma unroll
            for (int k = 0; k < CHUNK; ++k) {
                float val = row[k];
                float sq = val * val;               // x*x rounded separately
                asm volatile("" : "+v"(sq));        // block fma contraction
                r8[k & 7] += sq;
            }
            if (((hb >> 5) & 3) == 3) {             // end of a 128-elem block
                float s01 = r8[0] + r8[1], s23 = r8[2] + r8[3];
                float s45 = r8[4] + r8[5], s67 = r8[6] + r8[7];
                partial[t][hb >> 7] = (s01 + s23) + (s45 + s67);
                #pragma unroll
                for (int j = 0; j < 8; ++j) r8[j] = 0.0f;
            }
        } else if (t < 160) {
            float cs = 0.f;
            #pragma unroll
            for (int r = 0; r < 64; ++r) cs += xs[r][t - 128];
            colsum_part[blk * HDIM + hb + (t - 128)] = cs;
        }
        // ---- GEMM: sequential-k single-accumulator fmaf chain (f32) ----
        #pragma unroll
        for (int k = 0; k < CHUNK; ++k) {
            float ax[4], bw[4];
            #pragma unroll
            for (int i = 0; i < 4; ++i) ax[i] = xs[r0 + i][k];
            #pragma unroll
            for (int j = 0; j < 4; ++j) bw[j] = wsh[c0 + j][k];
            #pragma unroll
            for (int i = 0; i < 4; ++i)
                #pragma unroll
                for (int j = 0; j < 4; ++j)
                    acc[i][j] = __builtin_fmaf(ax[i], bw[j], acc[i][j]);
        }
    }
    // combine the 16 partials in numpy's balanced tree order
    if (t < 128) {
        float p[16];
        #pragma unroll
        for (int b = 0; b < 16; ++b) p[b] = partial[t][b];
        float t0 = p[0] + p[1],  t1 = p[2] + p[3],  t2 = p[4] + p[5],  t3 = p[6] + p[7];
        float t4 = p[8] + p[9],  t5 = p[10] + p[11], t6 = p[12] + p[13], t7 = p[14] + p[15];
        float u0 = t0 + t1, u1 = t2 + t3, u2 = t4 + t5, u3 = t6 + t7;
        nxw[t] = (u0 + u1) + (u2 + u3);
    }
    __syncthreads();
    #pragma unroll
    for (int i = 0; i < 4; ++i)
        #pragma unroll
        for (int j = 0; j < 4; ++j) {
            float s2  = nxw[r0 + i] + nxw[64 + c0 + j];  // fl(nx + nw)
            float tw  = 2.0f * acc[i][j];                // exact x2
            float d2  = s2 - tw;                         // fl(s2 - 2xw)
            C[r0 + i][c0 + j] = (double)sqrtf(fmaxf(d2, 0.0f));
        }
    __syncthreads();
    if (t != 0) return;

    // ---- literal scalar transliteration of the reference _lsa_square ----
    double u[65], v[65];
    int    p[65];
    int    ulist[66];
    bool   used[65];
    for (int j = 0; j <= 64; ++j) { u[j] = 0.0; v[j] = 0.0; p[j] = 0; }

    for (int i = 1; i <= 64; ++i) {
        for (int j = 0; j <= 64; ++j) used[j] = false;
        p[0] = i;
        int j0 = 0;
        int nu = 0;
        while (true) {
            used[j0] = true;
            ulist[nu++] = j0;
            int i0 = p[j0];
            double ui0 = u[i0];
            double best = __builtin_inf();
            int j1 = 1;
            for (int j = 1; j <= 64; ++j) {
                if (used[j]) continue;
                double cur = (C[i0 - 1][j - 1] - ui0) - v[j];
                if (cur < best) { best = cur; j1 = j; }
            }
            double delta = best;
            for (int k = 0; k < nu; ++k) {
                int j = ulist[k];
                u[p[j]] += delta;
                v[j]    -= delta;
            }
            j0 = j1;
            if (p[j0] == 0) break;
        }
        p[j0] = i;   // way == 0 everywhere -> augmentation collapses to this
    }
    for (int j = 1; j <= 64; ++j) {
        int row_local = p[j] - 1;
        idx_ws[blk * 64 + row_local]  = j - 1;
        out_idx[blk * 64 + row_local] = (float)(j - 1);
    }
}

// ---------------------------------------------------------------------------
// K2: quantized = w[idx], SSE = sum((x - q)^2)  (8 rows/block, 32 lanes/row)
// ---------------------------------------------------------------------------
__global__ __launch_bounds__(256) void gather_loss_kernel(
    const float* __restrict__ x, const float* __restrict__ w,
    const int* __restrict__ idx, float* __restrict__ out_q,
    double* __restrict__ sse_acc)
{
    int blk = blockIdx.x;
    int t = threadIdx.x;
    int rloc = t >> 5;
    int l32 = t & 31;
    int row = blk * 8 + rloc;
    int code = idx[row];
    const float4* xr = reinterpret_cast<const float4*>(x + (size_t)row * HDIM);
    const float4* wr = reinterpret_cast<const float4*>(w + (size_t)code * HDIM);
    float* qr = out_q + (size_t)row * HDIM;   // NOT 16B aligned (d_out+1) -> scalar stores
    double s = 0.0;
    for (int k = l32; k < HDIM / 4; k += 32) {
        float4 a = xr[k];
        float4 b = wr[k];
        qr[k * 4 + 0] = b.x; qr[k * 4 + 1] = b.y;
        qr[k * 4 + 2] = b.z; qr[k * 4 + 3] = b.w;
        double d0 = (double)a.x - (double)b.x, d1 = (double)a.y - (double)b.y;
        double d2 = (double)a.z - (double)b.z, d3 = (double)a.w - (double)b.w;
        s += d0 * d0 + d1 * d1 + d2 * d2 + d3 * d3;
    }
    #pragma unroll
    for (int off = 32; off; off >>= 1) s += __shfl_xor(s, off);
    if ((t & 63) == 0) unsafeAtomicAdd(sse_acc, s);
}

// ---------------------------------------------------------------------------
// K3: mean term + loss finalize
// ---------------------------------------------------------------------------
__global__ __launch_bounds__(256) void finalize_kernel(
    const float* __restrict__ w, const float* __restrict__ colsum_part,
    const double* __restrict__ sse_acc, float* __restrict__ out_loss)
{
    __shared__ double red[4];
    int t = threadIdx.x;
    double sq = 0.0;
    for (int h = t; h < HDIM; h += 256) {
        double xs_ = 0.0;
        for (int b = 0; b < NBLK; ++b) xs_ += (double)colsum_part[b * HDIM + h];
        double ws_ = 0.0;
        for (int c = 0; c < M_CODES; ++c) ws_ += (double)w[c * HDIM + h];
        double d = xs_ * (1.0 / (double)N_ROWS) - ws_ * (1.0 / (double)M_CODES);
        sq += d * d;
    }
    #pragma unroll
    for (int off = 32; off; off >>= 1) sq += __shfl_xor(sq, off);
    if ((t & 63) == 0) red[t >> 6] = sq;
    __syncthreads();
    if (t == 0) {
        double tot = red[0] + red[1] + red[2] + red[3];
        double loss = 1.25 * (sse_acc[0] / ((double)N_ROWS * (double)HDIM) + tot / (double)HDIM);
        out_loss[0] = (float)loss;
    }
}

extern "C" void kernel_launch(void* const* d_in, const int* in_sizes, int n_in,
                              void* d_out, int out_size, void* d_ws, size_t ws_size,
                              hipStream_t stream)
{
    const float* x = (const float*)d_in[0];
    const float* w = (const float*)d_in[1];
    float* out      = (float*)d_out;
    float* out_loss = out;
    float* out_q    = out + 1;
    float* out_idx  = out + 1 + (size_t)N_ROWS * HDIM;

    char* ws = (char*)d_ws;
    double* sse_acc     = (double*)ws;                         // 8 B
    float*  colsum_part = (float*)(ws + 256);                  // 2 MB
    int*    idx_ws      = (int*)(ws + 256 + (size_t)NBLK * HDIM * 4); // 64 KB

    hipMemsetAsync(sse_acc, 0, sizeof(double), stream);
    dist_lsa_kernel<<<NBLK, 256, 0, stream>>>(x, w, colsum_part, idx_ws, out_idx);
    gather_loss_kernel<<<N_ROWS / 8, 256, 0, stream>>>(x, w, idx_ws, out_q, sse_acc);
    finalize_kernel<<<1, 256, 0, stream>>>(w, colsum_part, sse_acc, out_loss);
}

// Round 6
// 918.443 us; speedup vs baseline: 4.8637x; 4.8637x over previous
//
#include <hip/hip_runtime.h>
#include <hip/hip_bf16.h>
#include <math.h>

#define N_ROWS 16384
#define HDIM   2048
#define M_CODES 64
#define NBLK   256      // N_ROWS / 64
#define CHUNK  32

// ---------------------------------------------------------------------------
// K1: per 64-row block: FLOAT32 distance matrix with BLAS-like rounding
// (sequential-k fmaf chain for x@w.T, numpy-pairwise f32 row norms), upcast
// to f64 -> wave-parallel greedy walk (bit-identical to the reference's buggy
// _lsa_square; proven: R2 wave version == R3 serial transliteration).
// Also emits per-block column-sum partials of x.
// ---------------------------------------------------------------------------
__global__ __launch_bounds__(256) void dist_lsa_kernel(
    const float* __restrict__ x, const float* __restrict__ w,
    float* __restrict__ colsum_part,   // [NBLK][HDIM]
    int*   __restrict__ idx_ws,        // [N_ROWS]
    float* __restrict__ out_idx)       // d_out + 1 + N*H
{
    __shared__ float  xs [64][CHUNK + 4];
    __shared__ float  wsh[64][CHUNK + 4];
    __shared__ double C[64][65];
    __shared__ float  partial[128][17];   // 16 x 128-block partials per row
    __shared__ float  nxw[128];           // final norms: [0..63]=x, [64..127]=w
    __shared__ double u_[65];
    __shared__ int    p_[65];

    const int t   = threadIdx.x;
    const int blk = blockIdx.x;
    const float* xb = x + (size_t)blk * 64 * HDIM;

    const int ty = t >> 4, tx = t & 15;
    const int r0 = ty * 4, c0 = tx * 4;
    float acc[4][4];
    #pragma unroll
    for (int i = 0; i < 4; ++i)
        #pragma unroll
        for (int j = 0; j < 4; ++j) acc[i][j] = 0.0f;

    // numpy pairwise 8-accumulator state (threads 0..127 own a row's norm)
    float r8[8];
    #pragma unroll
    for (int j = 0; j < 8; ++j) r8[j] = 0.0f;

    for (int hb = 0; hb < HDIM; hb += CHUNK) {
        __syncthreads();
        #pragma unroll
        for (int i = 0; i < 2; ++i) {
            int s = t * 2 + i;            // 0..511 float4 slots
            int r = s >> 3, c4 = s & 7;
            float4 vx = *reinterpret_cast<const float4*>(&xb[(size_t)r * HDIM + hb + c4 * 4]);
            *reinterpret_cast<float4*>(&xs[r][c4 * 4]) = vx;
            float4 vw = *reinterpret_cast<const float4*>(&w[(size_t)r * HDIM + hb + c4 * 4]);
            *reinterpret_cast<float4*>(&wsh[r][c4 * 4]) = vw;
        }
        __syncthreads();
        // ---- norms: numpy pairwise semantics, f32, NO fma contraction ----
        if (t < 128) {
            const float* row = (t < 64) ? &xs[t][0] : &wsh[t - 64][0];
            #pragma unroll
            for (int k = 0; k < CHUNK; ++k) {
                float val = row[k];
                float sq = val * val;               // x*x rounded separately
                asm volatile("" : "+v"(sq));        // block fma contraction
                r8[k & 7] += sq;
            }
            if (((hb >> 5) & 3) == 3) {             // end of a 128-elem block
                float s01 = r8[0] + r8[1], s23 = r8[2] + r8[3];
                float s45 = r8[4] + r8[5], s67 = r8[6] + r8[7];
                partial[t][hb >> 7] = (s01 + s23) + (s45 + s67);
                #pragma unroll
                for (int j = 0; j < 8; ++j) r8[j] = 0.0f;
            }
        } else if (t < 160) {
            float cs = 0.f;
            #pragma unroll
            for (int r = 0; r < 64; ++r) cs += xs[r][t - 128];
            colsum_part[blk * HDIM + hb + (t - 128)] = cs;
        }
        // ---- GEMM: sequential-k single-accumulator fmaf chain (f32) ----
        #pragma unroll
        for (int k = 0; k < CHUNK; ++k) {
            float ax[4], bw[4];
            #pragma unroll
            for (int i = 0; i < 4; ++i) ax[i] = xs[r0 + i][k];
            #pragma unroll
            for (int j = 0; j < 4; ++j) bw[j] = wsh[c0 + j][k];
            #pragma unroll
            for (int i = 0; i < 4; ++i)
                #pragma unroll
                for (int j = 0; j < 4; ++j)
                    acc[i][j] = __builtin_fmaf(ax[i], bw[j], acc[i][j]);
        }
    }
    // combine the 16 partials in numpy's balanced tree order
    if (t < 128) {
        float p[16];
        #pragma unroll
        for (int b = 0; b < 16; ++b) p[b] = partial[t][b];
        float t0 = p[0] + p[1],  t1 = p[2] + p[3],  t2 = p[4] + p[5],  t3 = p[6] + p[7];
        float t4 = p[8] + p[9],  t5 = p[10] + p[11], t6 = p[12] + p[13], t7 = p[14] + p[15];
        float u0 = t0 + t1, u1 = t2 + t3, u2 = t4 + t5, u3 = t6 + t7;
        nxw[t] = (u0 + u1) + (u2 + u3);
    }
    __syncthreads();
    #pragma unroll
    for (int i = 0; i < 4; ++i)
        #pragma unroll
        for (int j = 0; j < 4; ++j) {
            float s2  = nxw[r0 + i] + nxw[64 + c0 + j];  // fl(nx + nw)
            float tw  = 2.0f * acc[i][j];                // exact x2
            float d2  = s2 - tw;                         // fl(s2 - 2xw)
            C[r0 + i][c0 + j] = (double)sqrtf(fmaxf(d2, 0.0f));
        }
    __syncthreads();
    if (t >= 64) return;

    // ---- wave-parallel greedy walk (== reference's buggy _lsa_square) ----
    // Proven bit-identical to the serial transliteration (R2 vs R3).
    const int lane = t;
    const int col  = lane + 1;          // this lane owns column `col` (1..64)
    double vcol = 0.0;                  // v[col] in a register
    u_[lane] = 0.0; p_[lane] = 0;
    if (lane == 0) { u_[64] = 0.0; p_[64] = 0; }

    for (int i = 1; i <= 64; ++i) {
        if (lane == 0) p_[0] = i;
        bool used = false;
        int  myrow = 0;
        int  j0 = 0;
        while (true) {
            if (col == j0) { used = true; myrow = p_[col]; }  // p_ stable in path
            int i0 = p_[j0];                                  // uniform
            double cur = (C[i0 - 1][lane] - u_[i0]) - vcol;
            double mv = used ? __builtin_inf() : cur;
            int    mi = col;
            #pragma unroll
            for (int off = 32; off; off >>= 1) {              // np first-min tie-break
                double ov = __shfl_xor(mv, off);
                int    oi = __shfl_xor(mi, off);
                if (ov < mv || (ov == mv && oi < mi)) { mv = ov; mi = oi; }
            }
            // delta = mv (uniform), j1 = mi (uniform). Update BEFORE break;
            // used set = {0} U marked cols (j1 NOT yet included).
            if (lane == 0) u_[i] += mv;                       // p_[0] = i
            if (used) { u_[myrow] += mv; vcol -= mv; }        // distinct rows
            j0 = mi;
            if (p_[j0] == 0) break;
        }
        if (lane == 0) p_[j0] = i;                            // way==0 collapse
    }
    int row_local = p_[col] - 1;                // row assigned to this column
    int code = col - 1;
    idx_ws[blk * 64 + row_local]  = code;
    out_idx[blk * 64 + row_local] = (float)code;
}

// ---------------------------------------------------------------------------
// K2: quantized = w[idx], SSE = sum((x - q)^2)  (8 rows/block, 32 lanes/row)
// ---------------------------------------------------------------------------
__global__ __launch_bounds__(256) void gather_loss_kernel(
    const float* __restrict__ x, const float* __restrict__ w,
    const int* __restrict__ idx, float* __restrict__ out_q,
    double* __restrict__ sse_acc)
{
    int blk = blockIdx.x;
    int t = threadIdx.x;
    int rloc = t >> 5;
    int l32 = t & 31;
    int row = blk * 8 + rloc;
    int code = idx[row];
    const float4* xr = reinterpret_cast<const float4*>(x + (size_t)row * HDIM);
    const float4* wr = reinterpret_cast<const float4*>(w + (size_t)code * HDIM);
    float* qr = out_q + (size_t)row * HDIM;   // NOT 16B aligned (d_out+1) -> scalar stores
    double s = 0.0;
    for (int k = l32; k < HDIM / 4; k += 32) {
        float4 a = xr[k];
        float4 b = wr[k];
        qr[k * 4 + 0] = b.x; qr[k * 4 + 1] = b.y;
        qr[k * 4 + 2] = b.z; qr[k * 4 + 3] = b.w;
        double d0 = (double)a.x - (double)b.x, d1 = (double)a.y - (double)b.y;
        double d2 = (double)a.z - (double)b.z, d3 = (double)a.w - (double)b.w;
        s += d0 * d0 + d1 * d1 + d2 * d2 + d3 * d3;
    }
    #pragma unroll
    for (int off = 32; off; off >>= 1) s += __shfl_xor(s, off);
    if ((t & 63) == 0) unsafeAtomicAdd(sse_acc, s);
}

// ---------------------------------------------------------------------------
// K3: mean term + loss finalize
// ---------------------------------------------------------------------------
__global__ __launch_bounds__(256) void finalize_kernel(
    const float* __restrict__ w, const float* __restrict__ colsum_part,
    const double* __restrict__ sse_acc, float* __restrict__ out_loss)
{
    __shared__ double red[4];
    int t = threadIdx.x;
    double sq = 0.0;
    for (int h = t; h < HDIM; h += 256) {
        double xs_ = 0.0;
        for (int b = 0; b < NBLK; ++b) xs_ += (double)colsum_part[b * HDIM + h];
        double ws_ = 0.0;
        for (int c = 0; c < M_CODES; ++c) ws_ += (double)w[c * HDIM + h];
        double d = xs_ * (1.0 / (double)N_ROWS) - ws_ * (1.0 / (double)M_CODES);
        sq += d * d;
    }
    #pragma unroll
    for (int off = 32; off; off >>= 1) sq += __shfl_xor(sq, off);
    if ((t & 63) == 0) red[t >> 6] = sq;
    __syncthreads();
    if (t == 0) {
        double tot = red[0] + red[1] + red[2] + red[3];
        double loss = 1.25 * (sse_acc[0] / ((double)N_ROWS * (double)HDIM) + tot / (double)HDIM);
        out_loss[0] = (float)loss;
    }
}

extern "C" void kernel_launch(void* const* d_in, const int* in_sizes, int n_in,
                              void* d_out, int out_size, void* d_ws, size_t ws_size,
                              hipStream_t stream)
{
    const float* x = (const float*)d_in[0];
    const float* w = (const float*)d_in[1];
    float* out      = (float*)d_out;
    float* out_loss = out;
    float* out_q    = out + 1;
    float* out_idx  = out + 1 + (size_t)N_ROWS * HDIM;

    char* ws = (char*)d_ws;
    double* sse_acc     = (double*)ws;                         // 8 B
    float*  colsum_part = (float*)(ws + 256);                  // 2 MB
    int*    idx_ws      = (int*)(ws + 256 + (size_t)NBLK * HDIM * 4); // 64 KB

    hipMemsetAsync(sse_acc, 0, sizeof(double), stream);
    dist_lsa_kernel<<<NBLK, 256, 0, stream>>>(x, w, colsum_part, idx_ws, out_idx);
    gather_loss_kernel<<<N_ROWS / 8, 256, 0, stream>>>(x, w, idx_ws, out_q, sse_acc);
    finalize_kernel<<<1, 256, 0, stream>>>(w, colsum_part, sse_acc, out_loss);
}

// Round 8
// 841.450 us; speedup vs baseline: 5.3087x; 1.0915x over previous
//
#include <hip/hip_runtime.h>
#include <hip/hip_bf16.h>
#include <math.h>

#define N_ROWS 16384
#define HDIM   2048
#define M_CODES 64
#define NBLK   256      // N_ROWS / 64
#define CHUNK  32
#define TP     68       // transposed LDS row stride (floats); 16B-aligned rows,
                        // conflict-free b128 GEMM reads, 2-way (free) staging writes

// ---------------------------------------------------------------------------
// K1: per 64-row block: FLOAT32 distance matrix with BLAS-like rounding
// (sequential-k fmaf chain for x@w.T, numpy-pairwise f32 row norms), f32 C ->
// wave-parallel greedy walk (bit-identical to the reference's buggy
// _lsa_square; proven R2==R3). Transposed LDS tiles [k][row] so GEMM operand
// reads are conflict-free ds_read_b128; register double-buffered staging.
// ---------------------------------------------------------------------------
__global__ __launch_bounds__(256) void dist_lsa_kernel(
    const float* __restrict__ x, const float* __restrict__ w,
    float* __restrict__ colsum_part,   // [NBLK][HDIM]
    int*   __restrict__ idx_ws,        // [N_ROWS]
    float* __restrict__ out_idx)       // d_out + 1 + N*H
{
    __shared__ float  xt[2][CHUNK][TP];   // x^T chunk: [buf][k][row]
    __shared__ float  wt[2][CHUNK][TP];   // w^T chunk: [buf][k][col]
    __shared__ float  Cs[64][65];
    __shared__ float  partial[128][17];   // 16 x 128-block norm partials per row
    __shared__ float  nxw[128];           // [0..63]=x norms, [64..127]=w norms
    __shared__ double u_[65];
    __shared__ int    p_[65];

    const int t   = threadIdx.x;
    const int blk = blockIdx.x;
    const float* xb = x + (size_t)blk * 64 * HDIM;

    const int ty = t >> 4, tx = t & 15;       // 16x16 thread grid
    const int r0 = ty * 4, c0 = tx * 4;       // 4x4 output tile

    // staging slots: slot = i*256 + t -> row = slot>>3, k4 = slot&7 (coalesced)
    const int sk4 = t & 7;
    const int sr0 = t >> 3;                   // i=0: rows 0..31
    const int sr1 = 32 + (t >> 3);            // i=1: rows 32..63

    float acc[4][4];
    #pragma unroll
    for (int i = 0; i < 4; ++i)
        #pragma unroll
        for (int j = 0; j < 4; ++j) acc[i][j] = 0.0f;

    // numpy pairwise 8-accumulator state (threads 0..127 own a row's norm)
    float r8[8];
    #pragma unroll
    for (int j = 0; j < 8; ++j) r8[j] = 0.0f;

    // ---- prologue: stage chunk 0 ----
    {
        float4 px0 = *reinterpret_cast<const float4*>(&xb[(size_t)sr0 * HDIM + sk4 * 4]);
        float4 px1 = *reinterpret_cast<const float4*>(&xb[(size_t)sr1 * HDIM + sk4 * 4]);
        float4 pw0 = *reinterpret_cast<const float4*>(&w [(size_t)sr0 * HDIM + sk4 * 4]);
        float4 pw1 = *reinterpret_cast<const float4*>(&w [(size_t)sr1 * HDIM + sk4 * 4]);
        #pragma unroll
        for (int d = 0; d < 4; ++d) {
            xt[0][sk4 * 4 + d][sr0] = ((const float*)&px0)[d];
            xt[0][sk4 * 4 + d][sr1] = ((const float*)&px1)[d];
            wt[0][sk4 * 4 + d][sr0] = ((const float*)&pw0)[d];
            wt[0][sk4 * 4 + d][sr1] = ((const float*)&pw1)[d];
        }
    }
    __syncthreads();

    for (int c = 0; c < 64; ++c) {
        const int cur = c & 1;
        const int hb  = c * CHUNK;

        // issue next chunk's global loads early (latency hides under compute)
        float4 nx0, nx1, nw0, nw1;
        const bool more = (c + 1 < 64);
        if (more) {
            const int nhb = hb + CHUNK;
            nx0 = *reinterpret_cast<const float4*>(&xb[(size_t)sr0 * HDIM + nhb + sk4 * 4]);
            nx1 = *reinterpret_cast<const float4*>(&xb[(size_t)sr1 * HDIM + nhb + sk4 * 4]);
            nw0 = *reinterpret_cast<const float4*>(&w [(size_t)sr0 * HDIM + nhb + sk4 * 4]);
            nw1 = *reinterpret_cast<const float4*>(&w [(size_t)sr1 * HDIM + nhb + sk4 * 4]);
        }

        // ---- GEMM: sequential-k fmaf chain, b128 conflict-free reads ----
        #pragma unroll
        for (int k = 0; k < CHUNK; ++k) {
            float4 a4 = *reinterpret_cast<const float4*>(&xt[cur][k][r0]);
            float4 b4 = *reinterpret_cast<const float4*>(&wt[cur][k][c0]);
            const float* ax = (const float*)&a4;
            const float* bw = (const float*)&b4;
            #pragma unroll
            for (int i = 0; i < 4; ++i)
                #pragma unroll
                for (int j = 0; j < 4; ++j)
                    acc[i][j] = __builtin_fmaf(ax[i], bw[j], acc[i][j]);
        }

        // ---- norms: numpy pairwise semantics, f32, NO fma contraction ----
        if (t < 128) {
            const float* base = (t < 64) ? &xt[cur][0][t] : &wt[cur][0][t - 64];
            #pragma unroll
            for (int k = 0; k < CHUNK; ++k) {
                float val = base[k * TP];
                float sq = val * val;               // x*x rounded separately
                asm volatile("" : "+v"(sq));        // block fma contraction
                r8[k & 7] += sq;
            }
            if ((c & 3) == 3) {                     // end of a 128-elem block
                float s01 = r8[0] + r8[1], s23 = r8[2] + r8[3];
                float s45 = r8[4] + r8[5], s67 = r8[6] + r8[7];
                partial[t][c >> 2] = (s01 + s23) + (s45 + s67);
                #pragma unroll
                for (int j = 0; j < 8; ++j) r8[j] = 0.0f;
            }
        } else if (t < 160) {
            const float* row = &xt[cur][t - 128][0];
            float cs = 0.f;
            #pragma unroll
            for (int r = 0; r < 64; ++r) cs += row[r];
            colsum_part[blk * HDIM + hb + (t - 128)] = cs;
        }

        // ---- write next chunk into the other buffer (no extra barrier) ----
        if (more) {
            const int nb = cur ^ 1;
            #pragma unroll
            for (int d = 0; d < 4; ++d) {
                xt[nb][sk4 * 4 + d][sr0] = ((const float*)&nx0)[d];
                xt[nb][sk4 * 4 + d][sr1] = ((const float*)&nx1)[d];
                wt[nb][sk4 * 4 + d][sr0] = ((const float*)&nw0)[d];
                wt[nb][sk4 * 4 + d][sr1] = ((const float*)&nw1)[d];
            }
        }
        __syncthreads();
    }

    // combine the 16 partials in numpy's balanced tree order
    if (t < 128) {
        float p[16];
        #pragma unroll
        for (int b = 0; b < 16; ++b) p[b] = partial[t][b];
        float t0 = p[0] + p[1],  t1 = p[2] + p[3],  t2 = p[4] + p[5],  t3 = p[6] + p[7];
        float t4 = p[8] + p[9],  t5 = p[10] + p[11], t6 = p[12] + p[13], t7 = p[14] + p[15];
        float u0 = t0 + t1, u1 = t2 + t3, u2 = t4 + t5, u3 = t6 + t7;
        nxw[t] = (u0 + u1) + (u2 + u3);
    }
    __syncthreads();
    #pragma unroll
    for (int i = 0; i < 4; ++i)
        #pragma unroll
        for (int j = 0; j < 4; ++j) {
            float s2  = nxw[r0 + i] + nxw[64 + c0 + j];  // fl(nx + nw)
            float tw  = 2.0f * acc[i][j];                // exact x2
            float d2  = s2 - tw;                         // fl(s2 - 2xw)
            Cs[r0 + i][c0 + j] = sqrtf(fmaxf(d2, 0.0f)); // f32-exact value
        }
    __syncthreads();
    if (t >= 64) return;

    // ---- wave-parallel greedy walk (== reference's buggy _lsa_square) ----
    // Proven bit-identical to the serial transliteration (R2 vs R3).
    const int lane = t;
    const int col  = lane + 1;          // this lane owns column `col` (1..64)
    double vcol = 0.0;                  // v[col] in a register
    u_[lane] = 0.0; p_[lane] = 0;
    if (lane == 0) { u_[64] = 0.0; p_[64] = 0; }

    for (int i = 1; i <= 64; ++i) {
        if (lane == 0) p_[0] = i;
        bool used = false;
        int  myrow = 0;
        int  j0 = 0;
        while (true) {
            if (col == j0) { used = true; myrow = p_[col]; }  // p_ stable in path
            int i0 = p_[j0];                                  // uniform
            double cur = ((double)Cs[i0 - 1][lane] - u_[i0]) - vcol;
            double mv = used ? __builtin_inf() : cur;
            int    mi = col;
            #pragma unroll
            for (int off = 32; off; off >>= 1) {              // np first-min tie-break
                double ov = __shfl_xor(mv, off);
                int    oi = __shfl_xor(mi, off);
                if (ov < mv || (ov == mv && oi < mi)) { mv = ov; mi = oi; }
            }
            // delta = mv (uniform), j1 = mi (uniform). Update BEFORE break;
            // used set = {0} U marked cols (j1 NOT yet included).
            if (lane == 0) u_[i] += mv;                       // p_[0] = i
            if (used) { u_[myrow] += mv; vcol -= mv; }        // distinct rows
            j0 = mi;
            if (p_[j0] == 0) break;
        }
        if (lane == 0) p_[j0] = i;                            // way==0 collapse
    }
    int row_local = p_[col] - 1;                // row assigned to this column
    int code = col - 1;
    idx_ws[blk * 64 + row_local]  = code;
    out_idx[blk * 64 + row_local] = (float)code;
}

// ---------------------------------------------------------------------------
// K2: quantized = w[idx], SSE = sum((x - q)^2)  (8 rows/block, 32 lanes/row)
// ---------------------------------------------------------------------------
__global__ __launch_bounds__(256) void gather_loss_kernel(
    const float* __restrict__ x, const float* __restrict__ w,
    const int* __restrict__ idx, float* __restrict__ out_q,
    double* __restrict__ sse_acc)
{
    int blk = blockIdx.x;
    int t = threadIdx.x;
    int rloc = t >> 5;
    int l32 = t & 31;
    int row = blk * 8 + rloc;
    int code = idx[row];
    const float4* xr = reinterpret_cast<const float4*>(x + (size_t)row * HDIM);
    const float4* wr = reinterpret_cast<const float4*>(w + (size_t)code * HDIM);
    float* qr = out_q + (size_t)row * HDIM;   // NOT 16B aligned (d_out+1) -> scalar stores
    double s = 0.0;
    for (int k = l32; k < HDIM / 4; k += 32) {
        float4 a = xr[k];
        float4 b = wr[k];
        qr[k * 4 + 0] = b.x; qr[k * 4 + 1] = b.y;
        qr[k * 4 + 2] = b.z; qr[k * 4 + 3] = b.w;
        double d0 = (double)a.x - (double)b.x, d1 = (double)a.y - (double)b.y;
        double d2 = (double)a.z - (double)b.z, d3 = (double)a.w - (double)b.w;
        s += d0 * d0 + d1 * d1 + d2 * d2 + d3 * d3;
    }
    #pragma unroll
    for (int off = 32; off; off >>= 1) s += __shfl_xor(s, off);
    if ((t & 63) == 0) unsafeAtomicAdd(sse_acc, s);
}

// ---------------------------------------------------------------------------
// K3: mean term + loss finalize
// ---------------------------------------------------------------------------
__global__ __launch_bounds__(256) void finalize_kernel(
    const float* __restrict__ w, const float* __restrict__ colsum_part,
    const double* __restrict__ sse_acc, float* __restrict__ out_loss)
{
    __shared__ double red[4];
    int t = threadIdx.x;
    double sq = 0.0;
    for (int h = t; h < HDIM; h += 256) {
        double xs_ = 0.0;
        for (int b = 0; b < NBLK; ++b) xs_ += (double)colsum_part[b * HDIM + h];
        double ws_ = 0.0;
        for (int c = 0; c < M_CODES; ++c) ws_ += (double)w[c * HDIM + h];
        double d = xs_ * (1.0 / (double)N_ROWS) - ws_ * (1.0 / (double)M_CODES);
        sq += d * d;
    }
    #pragma unroll
    for (int off = 32; off; off >>= 1) sq += __shfl_xor(sq, off);
    if ((t & 63) == 0) red[t >> 6] = sq;
    __syncthreads();
    if (t == 0) {
        double tot = red[0] + red[1] + red[2] + red[3];
        double loss = 1.25 * (sse_acc[0] / ((double)N_ROWS * (double)HDIM) + tot / (double)HDIM);
        out_loss[0] = (float)loss;
    }
}

extern "C" void kernel_launch(void* const* d_in, const int* in_sizes, int n_in,
                              void* d_out, int out_size, void* d_ws, size_t ws_size,
                              hipStream_t stream)
{
    const float* x = (const float*)d_in[0];
    const float* w = (const float*)d_in[1];
    float* out      = (float*)d_out;
    float* out_loss = out;
    float* out_q    = out + 1;
    float* out_idx  = out + 1 + (size_t)N_ROWS * HDIM;

    char* ws = (char*)d_ws;
    double* sse_acc     = (double*)ws;                         // 8 B
    float*  colsum_part = (float*)(ws + 256);                  // 2 MB
    int*    idx_ws      = (int*)(ws + 256 + (size_t)NBLK * HDIM * 4); // 64 KB

    hipMemsetAsync(sse_acc, 0, sizeof(double), stream);
    dist_lsa_kernel<<<NBLK, 256, 0, stream>>>(x, w, colsum_part, idx_ws, out_idx);
    gather_loss_kernel<<<N_ROWS / 8, 256, 0, stream>>>(x, w, idx_ws, out_q, sse_acc);
    finalize_kernel<<<1, 256, 0, stream>>>(w, colsum_part, sse_acc, out_loss);
}

// Round 10
// 678.498 us; speedup vs baseline: 6.5837x; 1.2402x over previous
//
#include <hip/hip_runtime.h>
#include <hip/hip_bf16.h>
#include <math.h>

#define N_ROWS 16384
#define HDIM   2048
#define M_CODES 64
#define NBLK   256      // N_ROWS / 64
#define CHUNK  32
#define TP     68       // transposed LDS row stride (floats)

// ---------------------------------------------------------------------------
// K1 (fused): per 64-row block: FLOAT32 distance matrix with BLAS-like
// rounding (sequential-k fmaf chain for x@w.T, numpy-pairwise f32 row norms)
// -> LDS Cs[64][65] -> wave-parallel greedy walk (== reference's buggy
// _lsa_square; proven bit-identical R2==R3). Solver state (p, u, v, row->col)
// lives in lane-distributed registers; argmin butterfly uses DPP row_ror for
// offsets 1/2/4/8 (VALU speed) + shfl_xor for 16/32.
// ---------------------------------------------------------------------------
__global__ __launch_bounds__(256) void dist_lsa_kernel(
    const float* __restrict__ x, const float* __restrict__ w,
    float* __restrict__ colsum_part,   // [NBLK][HDIM]
    int*   __restrict__ idx_ws,        // [N_ROWS]
    float* __restrict__ out_idx)       // d_out + 1 + N*H
{
    __shared__ float  xt[2][CHUNK][TP];   // x^T chunk: [buf][k][row]
    __shared__ float  wt[2][CHUNK][TP];   // w^T chunk: [buf][k][col]
    __shared__ float  Cs[64][65];
    __shared__ float  partial[128][17];   // 16 x 128-block norm partials per row
    __shared__ float  nxw[128];           // [0..63]=x norms, [64..127]=w norms

    const int t   = threadIdx.x;
    const int blk = blockIdx.x;
    const float* xb = x + (size_t)blk * 64 * HDIM;

    const int ty = t >> 4, tx = t & 15;       // 16x16 thread grid
    const int r0 = ty * 4, c0 = tx * 4;       // 4x4 output tile

    const int sk4 = t & 7;
    const int sr0 = t >> 3;                   // rows 0..31
    const int sr1 = 32 + (t >> 3);            // rows 32..63

    float acc[4][4];
    #pragma unroll
    for (int i = 0; i < 4; ++i)
        #pragma unroll
        for (int j = 0; j < 4; ++j) acc[i][j] = 0.0f;

    float r8[8];
    #pragma unroll
    for (int j = 0; j < 8; ++j) r8[j] = 0.0f;

    // ---- prologue: stage chunk 0 ----
    {
        float4 px0 = *reinterpret_cast<const float4*>(&xb[(size_t)sr0 * HDIM + sk4 * 4]);
        float4 px1 = *reinterpret_cast<const float4*>(&xb[(size_t)sr1 * HDIM + sk4 * 4]);
        float4 pw0 = *reinterpret_cast<const float4*>(&w [(size_t)sr0 * HDIM + sk4 * 4]);
        float4 pw1 = *reinterpret_cast<const float4*>(&w [(size_t)sr1 * HDIM + sk4 * 4]);
        #pragma unroll
        for (int d = 0; d < 4; ++d) {
            xt[0][sk4 * 4 + d][sr0] = ((const float*)&px0)[d];
            xt[0][sk4 * 4 + d][sr1] = ((const float*)&px1)[d];
            wt[0][sk4 * 4 + d][sr0] = ((const float*)&pw0)[d];
            wt[0][sk4 * 4 + d][sr1] = ((const float*)&pw1)[d];
        }
    }
    __syncthreads();

    for (int c = 0; c < 64; ++c) {
        const int cur = c & 1;
        const int hb  = c * CHUNK;

        float4 nx0, nx1, nw0, nw1;
        const bool more = (c + 1 < 64);
        if (more) {
            const int nhb = hb + CHUNK;
            nx0 = *reinterpret_cast<const float4*>(&xb[(size_t)sr0 * HDIM + nhb + sk4 * 4]);
            nx1 = *reinterpret_cast<const float4*>(&xb[(size_t)sr1 * HDIM + nhb + sk4 * 4]);
            nw0 = *reinterpret_cast<const float4*>(&w [(size_t)sr0 * HDIM + nhb + sk4 * 4]);
            nw1 = *reinterpret_cast<const float4*>(&w [(size_t)sr1 * HDIM + nhb + sk4 * 4]);
        }

        // ---- GEMM: sequential-k fmaf chain, b128 conflict-free reads ----
        #pragma unroll
        for (int k = 0; k < CHUNK; ++k) {
            float4 a4 = *reinterpret_cast<const float4*>(&xt[cur][k][r0]);
            float4 b4 = *reinterpret_cast<const float4*>(&wt[cur][k][c0]);
            const float* ax = (const float*)&a4;
            const float* bw = (const float*)&b4;
            #pragma unroll
            for (int i = 0; i < 4; ++i)
                #pragma unroll
                for (int j = 0; j < 4; ++j)
                    acc[i][j] = __builtin_fmaf(ax[i], bw[j], acc[i][j]);
        }

        // ---- norms: numpy pairwise semantics, f32, NO fma contraction ----
        if (t < 128) {
            const float* base = (t < 64) ? &xt[cur][0][t] : &wt[cur][0][t - 64];
            #pragma unroll
            for (int k = 0; k < CHUNK; ++k) {
                float val = base[k * TP];
                float sq = val * val;               // x*x rounded separately
                asm volatile("" : "+v"(sq));        // block fma contraction
                r8[k & 7] += sq;
            }
            if ((c & 3) == 3) {                     // end of a 128-elem block
                float s01 = r8[0] + r8[1], s23 = r8[2] + r8[3];
                float s45 = r8[4] + r8[5], s67 = r8[6] + r8[7];
                partial[t][c >> 2] = (s01 + s23) + (s45 + s67);
                #pragma unroll
                for (int j = 0; j < 8; ++j) r8[j] = 0.0f;
            }
        } else if (t < 160) {
            const float* row = &xt[cur][t - 128][0];
            float cs = 0.f;
            #pragma unroll
            for (int r = 0; r < 64; ++r) cs += row[r];
            colsum_part[blk * HDIM + hb + (t - 128)] = cs;
        }

        if (more) {
            const int nb = cur ^ 1;
            #pragma unroll
            for (int d = 0; d < 4; ++d) {
                xt[nb][sk4 * 4 + d][sr0] = ((const float*)&nx0)[d];
                xt[nb][sk4 * 4 + d][sr1] = ((const float*)&nx1)[d];
                wt[nb][sk4 * 4 + d][sr0] = ((const float*)&nw0)[d];
                wt[nb][sk4 * 4 + d][sr1] = ((const float*)&nw1)[d];
            }
        }
        __syncthreads();
    }

    // combine the 16 partials in numpy's balanced tree order
    if (t < 128) {
        float p[16];
        #pragma unroll
        for (int b = 0; b < 16; ++b) p[b] = partial[t][b];
        float t0 = p[0] + p[1],  t1 = p[2] + p[3],  t2 = p[4] + p[5],  t3 = p[6] + p[7];
        float t4 = p[8] + p[9],  t5 = p[10] + p[11], t6 = p[12] + p[13], t7 = p[14] + p[15];
        float u0 = t0 + t1, u1 = t2 + t3, u2 = t4 + t5, u3 = t6 + t7;
        nxw[t] = (u0 + u1) + (u2 + u3);
    }
    __syncthreads();
    #pragma unroll
    for (int i = 0; i < 4; ++i)
        #pragma unroll
        for (int j = 0; j < 4; ++j) {
            float s2  = nxw[r0 + i] + nxw[64 + c0 + j];  // fl(nx + nw)
            float tw  = 2.0f * acc[i][j];                // exact x2
            float d2  = s2 - tw;                         // fl(s2 - 2xw)
            Cs[r0 + i][c0 + j] = sqrtf(fmaxf(d2, 0.0f)); // f32-exact value
        }
    __syncthreads();
    if (t >= 64) return;

    // ---- register-state greedy walk (== reference's buggy _lsa_square) ----
    // lane L owns: col L+1's v (vcol) + used flag; row L+1's u (uown) and
    // assigned column (ic); p[L+1] (pown).
    const int lane = t;
    int    pown = 0;     // p[lane+1]
    double uown = 0.0;   // u[lane+1]
    double vcol = 0.0;   // v[lane+1]
    int    ic   = 0;     // column assigned to row lane+1 (0 = none yet)

#define DPP_STAGE(CTRL) do {                                                     \
        int nlo = __builtin_amdgcn_update_dpp(0, __double2loint(mv), (CTRL), 0xf, 0xf, false); \
        int nhi = __builtin_amdgcn_update_dpp(0, __double2hiint(mv), (CTRL), 0xf, 0xf, false); \
        int nmi = __builtin_amdgcn_update_dpp(0, mi, (CTRL), 0xf, 0xf, false);   \
        double nv = __hiloint2double(nhi, nlo);                                  \
        if (nv < mv || (nv == mv && nmi < mi)) { mv = nv; mi = nmi; }            \
    } while (0)

    for (int i = 1; i <= 64; ++i) {
        bool used = false;
        int  j0 = 0;
        int  i0 = i;                           // p[0] = i
        while (true) {
            if (lane == j0 - 1) used = true;   // mark col j0 (j0 >= 1)
            int uhi = __builtin_amdgcn_readlane(__double2hiint(uown), i0 - 1);
            int ulo = __builtin_amdgcn_readlane(__double2loint(uown), i0 - 1);
            double u_i0 = __hiloint2double(uhi, ulo);
            double cur = ((double)Cs[i0 - 1][lane] - u_i0) - vcol;
            double mv = used ? __builtin_inf() : cur;
            int    mi = lane + 1;
            // lexmin (value, index) over 64 lanes; np first-min tie-break.
            DPP_STAGE(0x121);   // row_ror:1  (row-of-16 window 2)
            DPP_STAGE(0x122);   // row_ror:2  (window 4)
            DPP_STAGE(0x124);   // row_ror:4  (window 8)
            DPP_STAGE(0x128);   // row_ror:8  (full row of 16)
            #pragma unroll
            for (int off = 16; off <= 32; off <<= 1) {
                double ov = __shfl_xor(mv, off);
                int    oi = __shfl_xor(mi, off);
                if (ov < mv || (ov == mv && oi < mi)) { mv = ov; mi = oi; }
            }
            // delta = mv (uniform). u[p[j]] += delta for used j (incl. j=0 ->
            // u[i]); v[used] -= delta. Rows of used cols tracked via ic/ballot.
            unsigned long long ball = __ballot(used);
            bool onpath = (ic != 0) && ((ball >> (ic - 1)) & 1ull);
            if (onpath || lane == i - 1) uown += mv;
            if (used) vcol -= mv;
            j0 = __builtin_amdgcn_readfirstlane(mi);
            int pj = __builtin_amdgcn_readlane(pown, j0 - 1);
            if (pj == 0) break;
            i0 = pj;
        }
        if (lane == j0 - 1) pown = i;          // way==0 collapse: p[j_final] = i
        if (lane == i - 1)  ic = j0;           // row i now assigned column j0
    }
#undef DPP_STAGE
    int row_local = pown - 1;                  // row assigned to col lane+1
    idx_ws[blk * 64 + row_local]  = lane;
    out_idx[blk * 64 + row_local] = (float)lane;
}

// ---------------------------------------------------------------------------
// K2: quantized = w[idx], SSE = sum((x - q)^2)  (8 rows/block, 32 lanes/row)
// ---------------------------------------------------------------------------
__global__ __launch_bounds__(256) void gather_loss_kernel(
    const float* __restrict__ x, const float* __restrict__ w,
    const int* __restrict__ idx, float* __restrict__ out_q,
    double* __restrict__ sse_acc)
{
    int blk = blockIdx.x;
    int t = threadIdx.x;
    int rloc = t >> 5;
    int l32 = t & 31;
    int row = blk * 8 + rloc;
    int code = idx[row];
    const float4* xr = reinterpret_cast<const float4*>(x + (size_t)row * HDIM);
    const float4* wr = reinterpret_cast<const float4*>(w + (size_t)code * HDIM);
    float* qr = out_q + (size_t)row * HDIM;   // NOT 16B aligned (d_out+1) -> scalar stores
    double s = 0.0;
    for (int k = l32; k < HDIM / 4; k += 32) {
        float4 a = xr[k];
        float4 b = wr[k];
        qr[k * 4 + 0] = b.x; qr[k * 4 + 1] = b.y;
        qr[k * 4 + 2] = b.z; qr[k * 4 + 3] = b.w;
        double d0 = (double)a.x - (double)b.x, d1 = (double)a.y - (double)b.y;
        double d2 = (double)a.z - (double)b.z, d3 = (double)a.w - (double)b.w;
        s += d0 * d0 + d1 * d1 + d2 * d2 + d3 * d3;
    }
    #pragma unroll
    for (int off = 32; off; off >>= 1) s += __shfl_xor(s, off);
    if ((t & 63) == 0) unsafeAtomicAdd(sse_acc, s);
}

// ---------------------------------------------------------------------------
// K3a: mean-term partials, parallel over h (8 blocks x 256 threads, 1 h each;
// b-loop and c-loop fully coalesced). Loss tolerance is loose -> any f64
// summation order is fine.
// ---------------------------------------------------------------------------
__global__ __launch_bounds__(256) void finalize_partial(
    const float* __restrict__ w, const float* __restrict__ colsum_part,
    double* __restrict__ mean_acc)
{
    int h = blockIdx.x * 256 + threadIdx.x;     // 0..2047
    double xs_ = 0.0;
    for (int b = 0; b < NBLK; ++b) xs_ += (double)colsum_part[(size_t)b * HDIM + h];
    double ws_ = 0.0;
    for (int c = 0; c < M_CODES; ++c) ws_ += (double)w[(size_t)c * HDIM + h];
    double d = xs_ * (1.0 / (double)N_ROWS) - ws_ * (1.0 / (double)M_CODES);
    double sq = d * d;
    #pragma unroll
    for (int off = 32; off; off >>= 1) sq += __shfl_xor(sq, off);
    if ((threadIdx.x & 63) == 0) unsafeAtomicAdd(mean_acc, sq);
}

// ---------------------------------------------------------------------------
// K3b: loss finalize
// ---------------------------------------------------------------------------
__global__ __launch_bounds__(64) void finalize_loss(
    const double* __restrict__ sse_acc, const double* __restrict__ mean_acc,
    float* __restrict__ out_loss)
{
    if (threadIdx.x == 0) {
        double loss = 1.25 * (sse_acc[0] / ((double)N_ROWS * (double)HDIM)
                              + mean_acc[0] / (double)HDIM);
        out_loss[0] = (float)loss;
    }
}

extern "C" void kernel_launch(void* const* d_in, const int* in_sizes, int n_in,
                              void* d_out, int out_size, void* d_ws, size_t ws_size,
                              hipStream_t stream)
{
    const float* x = (const float*)d_in[0];
    const float* w = (const float*)d_in[1];
    float* out      = (float*)d_out;
    float* out_loss = out;
    float* out_q    = out + 1;
    float* out_idx  = out + 1 + (size_t)N_ROWS * HDIM;

    char* ws = (char*)d_ws;
    double* sse_acc     = (double*)ws;                               // 8 B
    double* mean_acc    = (double*)(ws + 8);                         // 8 B
    float*  colsum_part = (float*)(ws + 256);                        // 2 MB [NBLK][HDIM]
    int*    idx_ws      = (int*)(ws + 256 + (size_t)NBLK * HDIM * 4); // 64 KB

    hipMemsetAsync(ws, 0, 16, stream);
    dist_lsa_kernel<<<NBLK, 256, 0, stream>>>(x, w, colsum_part, idx_ws, out_idx);
    gather_loss_kernel<<<N_ROWS / 8, 256, 0, stream>>>(x, w, idx_ws, out_q, sse_acc);
    finalize_partial<<<HDIM / 256, 256, 0, stream>>>(w, colsum_part, mean_acc);
    finalize_loss<<<1, 64, 0, stream>>>(sse_acc, mean_acc, out_loss);
}

// Round 11
// 576.306 us; speedup vs baseline: 7.7511x; 1.1773x over previous
//
#include <hip/hip_runtime.h>
#include <hip/hip_bf16.h>
#include <math.h>

#define N_ROWS 16384
#define HDIM   2048
#define M_CODES 64
#define NBLK   256      // N_ROWS / 64
#define CHUNK  32
#define TP     68       // transposed LDS row stride (floats)

// ---------------------------------------------------------------------------
// K1 (fused): per 64-row block: FLOAT32 distance matrix with BLAS-like
// rounding (sequential-k fmaf chain for x@w.T, numpy-pairwise f32 row norms)
// -> LDS Cs[64][65] -> wave-parallel greedy walk (== reference's buggy
// _lsa_square; proven bit-identical R2==R3). Solver state in lane-distributed
// registers; lexmin reduction entirely on VALU: 4x DPP row_ror (row of 16) +
// row_bcast15/row_bcast31 merges + readlane(63) broadcast. No LDS-pipe ops.
// ---------------------------------------------------------------------------
__global__ __launch_bounds__(256) void dist_lsa_kernel(
    const float* __restrict__ x, const float* __restrict__ w,
    float* __restrict__ colsum_part,   // [NBLK][HDIM]
    int*   __restrict__ idx_ws,        // [N_ROWS]
    float* __restrict__ out_idx)       // d_out + 1 + N*H
{
    __shared__ float  xt[2][CHUNK][TP];   // x^T chunk: [buf][k][row]
    __shared__ float  wt[2][CHUNK][TP];   // w^T chunk: [buf][k][col]
    __shared__ float  Cs[64][65];
    __shared__ float  partial[128][17];   // 16 x 128-block norm partials per row
    __shared__ float  nxw[128];           // [0..63]=x norms, [64..127]=w norms

    const int t   = threadIdx.x;
    const int blk = blockIdx.x;
    const float* xb = x + (size_t)blk * 64 * HDIM;

    const int ty = t >> 4, tx = t & 15;       // 16x16 thread grid
    const int r0 = ty * 4, c0 = tx * 4;       // 4x4 output tile

    const int sk4 = t & 7;
    const int sr0 = t >> 3;                   // rows 0..31
    const int sr1 = 32 + (t >> 3);            // rows 32..63

    float acc[4][4];
    #pragma unroll
    for (int i = 0; i < 4; ++i)
        #pragma unroll
        for (int j = 0; j < 4; ++j) acc[i][j] = 0.0f;

    float r8[8];
    #pragma unroll
    for (int j = 0; j < 8; ++j) r8[j] = 0.0f;

    // ---- prologue: stage chunk 0 ----
    {
        float4 px0 = *reinterpret_cast<const float4*>(&xb[(size_t)sr0 * HDIM + sk4 * 4]);
        float4 px1 = *reinterpret_cast<const float4*>(&xb[(size_t)sr1 * HDIM + sk4 * 4]);
        float4 pw0 = *reinterpret_cast<const float4*>(&w [(size_t)sr0 * HDIM + sk4 * 4]);
        float4 pw1 = *reinterpret_cast<const float4*>(&w [(size_t)sr1 * HDIM + sk4 * 4]);
        #pragma unroll
        for (int d = 0; d < 4; ++d) {
            xt[0][sk4 * 4 + d][sr0] = ((const float*)&px0)[d];
            xt[0][sk4 * 4 + d][sr1] = ((const float*)&px1)[d];
            wt[0][sk4 * 4 + d][sr0] = ((const float*)&pw0)[d];
            wt[0][sk4 * 4 + d][sr1] = ((const float*)&pw1)[d];
        }
    }
    __syncthreads();

    for (int c = 0; c < 64; ++c) {
        const int cur = c & 1;
        const int hb  = c * CHUNK;

        float4 nx0, nx1, nw0, nw1;
        const bool more = (c + 1 < 64);
        if (more) {
            const int nhb = hb + CHUNK;
            nx0 = *reinterpret_cast<const float4*>(&xb[(size_t)sr0 * HDIM + nhb + sk4 * 4]);
            nx1 = *reinterpret_cast<const float4*>(&xb[(size_t)sr1 * HDIM + nhb + sk4 * 4]);
            nw0 = *reinterpret_cast<const float4*>(&w [(size_t)sr0 * HDIM + nhb + sk4 * 4]);
            nw1 = *reinterpret_cast<const float4*>(&w [(size_t)sr1 * HDIM + nhb + sk4 * 4]);
        }

        // ---- GEMM: sequential-k fmaf chain, b128 conflict-free reads ----
        #pragma unroll
        for (int k = 0; k < CHUNK; ++k) {
            float4 a4 = *reinterpret_cast<const float4*>(&xt[cur][k][r0]);
            float4 b4 = *reinterpret_cast<const float4*>(&wt[cur][k][c0]);
            const float* ax = (const float*)&a4;
            const float* bw = (const float*)&b4;
            #pragma unroll
            for (int i = 0; i < 4; ++i)
                #pragma unroll
                for (int j = 0; j < 4; ++j)
                    acc[i][j] = __builtin_fmaf(ax[i], bw[j], acc[i][j]);
        }

        // ---- norms: numpy pairwise semantics, f32, NO fma contraction ----
        if (t < 128) {
            const float* base = (t < 64) ? &xt[cur][0][t] : &wt[cur][0][t - 64];
            #pragma unroll
            for (int k = 0; k < CHUNK; ++k) {
                float val = base[k * TP];
                float sq = val * val;               // x*x rounded separately
                asm volatile("" : "+v"(sq));        // block fma contraction
                r8[k & 7] += sq;
            }
            if ((c & 3) == 3) {                     // end of a 128-elem block
                float s01 = r8[0] + r8[1], s23 = r8[2] + r8[3];
                float s45 = r8[4] + r8[5], s67 = r8[6] + r8[7];
                partial[t][c >> 2] = (s01 + s23) + (s45 + s67);
                #pragma unroll
                for (int j = 0; j < 8; ++j) r8[j] = 0.0f;
            }
        } else if (t < 160) {
            const float* row = &xt[cur][t - 128][0];
            float cs = 0.f;
            #pragma unroll
            for (int r = 0; r < 64; ++r) cs += row[r];
            colsum_part[blk * HDIM + hb + (t - 128)] = cs;
        }

        if (more) {
            const int nb = cur ^ 1;
            #pragma unroll
            for (int d = 0; d < 4; ++d) {
                xt[nb][sk4 * 4 + d][sr0] = ((const float*)&nx0)[d];
                xt[nb][sk4 * 4 + d][sr1] = ((const float*)&nx1)[d];
                wt[nb][sk4 * 4 + d][sr0] = ((const float*)&nw0)[d];
                wt[nb][sk4 * 4 + d][sr1] = ((const float*)&nw1)[d];
            }
        }
        __syncthreads();
    }

    // combine the 16 partials in numpy's balanced tree order
    if (t < 128) {
        float p[16];
        #pragma unroll
        for (int b = 0; b < 16; ++b) p[b] = partial[t][b];
        float t0 = p[0] + p[1],  t1 = p[2] + p[3],  t2 = p[4] + p[5],  t3 = p[6] + p[7];
        float t4 = p[8] + p[9],  t5 = p[10] + p[11], t6 = p[12] + p[13], t7 = p[14] + p[15];
        float u0 = t0 + t1, u1 = t2 + t3, u2 = t4 + t5, u3 = t6 + t7;
        nxw[t] = (u0 + u1) + (u2 + u3);
    }
    __syncthreads();
    #pragma unroll
    for (int i = 0; i < 4; ++i)
        #pragma unroll
        for (int j = 0; j < 4; ++j) {
            float s2  = nxw[r0 + i] + nxw[64 + c0 + j];  // fl(nx + nw)
            float tw  = 2.0f * acc[i][j];                // exact x2
            float d2  = s2 - tw;                         // fl(s2 - 2xw)
            Cs[r0 + i][c0 + j] = sqrtf(fmaxf(d2, 0.0f)); // f32-exact value
        }
    __syncthreads();
    if (t >= 64) return;

    // ---- register-state greedy walk (== reference's buggy _lsa_square) ----
    // lane L owns: col L+1's v (vcol) + used flag; row L+1's u (uown) and
    // assigned column (ic); p[L+1] (pown).
    const int lane = t;
    int    pown = 0;     // p[lane+1]
    double uown = 0.0;   // u[lane+1]
    double vcol = 0.0;   // v[lane+1]
    int    ic   = 0;     // column assigned to row lane+1 (0 = none yet)

    // merge (nv,nmi) into (mv,mi): total-order lexmin, np first-min tie-break
#define DPP_MERGE(CTRL, RMASK) do {                                              \
        int nlo = __builtin_amdgcn_update_dpp(__double2loint(mv), __double2loint(mv), (CTRL), (RMASK), 0xf, false); \
        int nhi = __builtin_amdgcn_update_dpp(__double2hiint(mv), __double2hiint(mv), (CTRL), (RMASK), 0xf, false); \
        int nmi = __builtin_amdgcn_update_dpp(mi, mi, (CTRL), (RMASK), 0xf, false); \
        double nv = __hiloint2double(nhi, nlo);                                  \
        if (nv < mv || (nv == mv && nmi < mi)) { mv = nv; mi = nmi; }            \
    } while (0)

    for (int i = 1; i <= 64; ++i) {
        bool used = false;
        int  j0 = 0;
        int  i0 = i;                           // p[0] = i
        while (true) {
            if (lane == j0 - 1) used = true;   // mark col j0 (j0 >= 1)
            int uhi = __builtin_amdgcn_readlane(__double2hiint(uown), i0 - 1);
            int ulo = __builtin_amdgcn_readlane(__double2loint(uown), i0 - 1);
            double u_i0 = __hiloint2double(uhi, ulo);
            double cur = ((double)Cs[i0 - 1][lane] - u_i0) - vcol;
            double mv = used ? __builtin_inf() : cur;
            int    mi = lane + 1;
            // intra-row (16 lanes): every lane gets its row's lexmin
            DPP_MERGE(0x121, 0xf);   // row_ror:1
            DPP_MERGE(0x122, 0xf);   // row_ror:2
            DPP_MERGE(0x124, 0xf);   // row_ror:4
            DPP_MERGE(0x128, 0xf);   // row_ror:8
            // cross-row merges: rows 0->1, 2->3 (bcast15), then 0..1 -> 2,3
            // (bcast31). Lane 63 (row 3) ends with the global lexmin.
            DPP_MERGE(0x142, 0xa);   // row_bcast15 into rows 1,3
            DPP_MERGE(0x143, 0xc);   // row_bcast31 into rows 2,3
            int j0n = __builtin_amdgcn_readlane(mi, 63);
            int dlo = __builtin_amdgcn_readlane(__double2loint(mv), 63);
            int dhi = __builtin_amdgcn_readlane(__double2hiint(mv), 63);
            double delta = __hiloint2double(dhi, dlo);
            // u[p[j]] += delta for used j (incl. j=0 -> u[i]); v[used] -= delta.
            unsigned long long ball = __ballot(used);
            bool onpath = (ic != 0) && ((ball >> (ic - 1)) & 1ull);
            if (onpath || lane == i - 1) uown += delta;
            if (used) vcol -= delta;
            j0 = j0n;
            int pj = __builtin_amdgcn_readlane(pown, j0 - 1);
            if (pj == 0) break;
            i0 = pj;
        }
        if (lane == j0 - 1) pown = i;          // way==0 collapse: p[j_final] = i
        if (lane == i - 1)  ic = j0;           // row i now assigned column j0
    }
#undef DPP_MERGE
    int row_local = pown - 1;                  // row assigned to col lane+1
    idx_ws[blk * 64 + row_local]  = lane;
    out_idx[blk * 64 + row_local] = (float)lane;
}

// ---------------------------------------------------------------------------
// K2: quantized = w[idx], SSE = sum((x - q)^2)  (8 rows/block, 32 lanes/row)
// Cross-wave LDS reduce -> ONE f64 atomic per block.
// ---------------------------------------------------------------------------
__global__ __launch_bounds__(256) void gather_loss_kernel(
    const float* __restrict__ x, const float* __restrict__ w,
    const int* __restrict__ idx, float* __restrict__ out_q,
    double* __restrict__ sse_acc)
{
    __shared__ double wred[4];
    int blk = blockIdx.x;
    int t = threadIdx.x;
    int rloc = t >> 5;
    int l32 = t & 31;
    int row = blk * 8 + rloc;
    int code = idx[row];
    const float4* xr = reinterpret_cast<const float4*>(x + (size_t)row * HDIM);
    const float4* wr = reinterpret_cast<const float4*>(w + (size_t)code * HDIM);
    float* qr = out_q + (size_t)row * HDIM;   // NOT 16B aligned (d_out+1) -> scalar stores
    double s = 0.0;
    for (int k = l32; k < HDIM / 4; k += 32) {
        float4 a = xr[k];
        float4 b = wr[k];
        qr[k * 4 + 0] = b.x; qr[k * 4 + 1] = b.y;
        qr[k * 4 + 2] = b.z; qr[k * 4 + 3] = b.w;
        double d0 = (double)a.x - (double)b.x, d1 = (double)a.y - (double)b.y;
        double d2 = (double)a.z - (double)b.z, d3 = (double)a.w - (double)b.w;
        s += d0 * d0 + d1 * d1 + d2 * d2 + d3 * d3;
    }
    #pragma unroll
    for (int off = 32; off; off >>= 1) s += __shfl_xor(s, off);
    if ((t & 63) == 0) wred[t >> 6] = s;
    __syncthreads();
    if (t == 0) {
        double tot = (wred[0] + wred[1]) + (wred[2] + wred[3]);
        unsafeAtomicAdd(sse_acc, tot);
    }
}

// ---------------------------------------------------------------------------
// K3a: mean-term partials, parallel over h (8 blocks x 256 threads, 1 h each;
// b-loop and c-loop fully coalesced).
// ---------------------------------------------------------------------------
__global__ __launch_bounds__(256) void finalize_partial(
    const float* __restrict__ w, const float* __restrict__ colsum_part,
    double* __restrict__ mean_acc)
{
    int h = blockIdx.x * 256 + threadIdx.x;     // 0..2047
    double xs_ = 0.0;
    for (int b = 0; b < NBLK; ++b) xs_ += (double)colsum_part[(size_t)b * HDIM + h];
    double ws_ = 0.0;
    for (int c = 0; c < M_CODES; ++c) ws_ += (double)w[(size_t)c * HDIM + h];
    double d = xs_ * (1.0 / (double)N_ROWS) - ws_ * (1.0 / (double)M_CODES);
    double sq = d * d;
    #pragma unroll
    for (int off = 32; off; off >>= 1) sq += __shfl_xor(sq, off);
    if ((threadIdx.x & 63) == 0) unsafeAtomicAdd(mean_acc, sq);
}

// ---------------------------------------------------------------------------
// K3b: loss finalize
// ---------------------------------------------------------------------------
__global__ __launch_bounds__(64) void finalize_loss(
    const double* __restrict__ sse_acc, const double* __restrict__ mean_acc,
    float* __restrict__ out_loss)
{
    if (threadIdx.x == 0) {
        double loss = 1.25 * (sse_acc[0] / ((double)N_ROWS * (double)HDIM)
                              + mean_acc[0] / (double)HDIM);
        out_loss[0] = (float)loss;
    }
}

extern "C" void kernel_launch(void* const* d_in, const int* in_sizes, int n_in,
                              void* d_out, int out_size, void* d_ws, size_t ws_size,
                              hipStream_t stream)
{
    const float* x = (const float*)d_in[0];
    const float* w = (const float*)d_in[1];
    float* out      = (float*)d_out;
    float* out_loss = out;
    float* out_q    = out + 1;
    float* out_idx  = out + 1 + (size_t)N_ROWS * HDIM;

    char* ws = (char*)d_ws;
    double* sse_acc     = (double*)ws;                               // 8 B
    double* mean_acc    = (double*)(ws + 8);                         // 8 B
    float*  colsum_part = (float*)(ws + 256);                        // 2 MB [NBLK][HDIM]
    int*    idx_ws      = (int*)(ws + 256 + (size_t)NBLK * HDIM * 4); // 64 KB

    hipMemsetAsync(ws, 0, 16, stream);
    dist_lsa_kernel<<<NBLK, 256, 0, stream>>>(x, w, colsum_part, idx_ws, out_idx);
    gather_loss_kernel<<<N_ROWS / 8, 256, 0, stream>>>(x, w, idx_ws, out_q, sse_acc);
    finalize_partial<<<HDIM / 256, 256, 0, stream>>>(w, colsum_part, mean_acc);
    finalize_loss<<<1, 64, 0, stream>>>(sse_acc, mean_acc, out_loss);
}